// Round 1
// baseline (275.974 us; speedup 1.0000x reference)
//
#include <hip/hip_runtime.h>
#include <stdint.h>

// Problem constants (fixed by the reference setup_inputs)
#define BATCH 128
#define SEQN  384                         // a rows (DP rows i)
#define SEQM  384                         // b rows (DP columns j)
#define DIM   128
#define KINF   1000000.0f                 // reference pseudo-infinity (nat units)
#define LOG2E  1.4426950408889634f
#define LN2    0.6931471805599453f
#define KINF2  (KINF * LOG2E)             // pseudo-infinity in base-2-scaled units

// Fused producer/consumer geometry
#define RING    204                       // LDS ring capacity in D-columns
#define RSTRIDE 392                       // ushorts per ring column (384 + 8 pad -> conflict-free banks)
#define NCHUNK  13                        // chunks 0..11 = 32 cols MFMA each; chunk 12 = pad cols 384..387

// hardware base-2 transcendentals (v_exp_f32 / v_log_f32)
#define EXP2F(x) __builtin_amdgcn_exp2f(x)
#define LOG2F(x) __builtin_amdgcn_logf(x)

typedef __attribute__((ext_vector_type(8))) short bf16x8;   // 8 bf16 = 4 VGPRs (MFMA A/B frag)
typedef __attribute__((ext_vector_type(4))) float f32x4;    // MFMA C/D frag

__device__ __forceinline__ unsigned short bf16_rne(float x) {
    uint32_t u = __float_as_uint(x);
    u += 0x7FFFu + ((u >> 16) & 1u);
    return (unsigned short)(u >> 16);
}
__device__ __forceinline__ uint32_t bf16_pair(float x, float y) {
    uint32_t ux = __float_as_uint(x); ux += 0x7FFFu + ((ux >> 16) & 1u);
    uint32_t uy = __float_as_uint(y); uy += 0x7FFFu + ((uy >> 16) & 1u);
    return (ux >> 16) | (uy & 0xFFFF0000u);
}

union frag_u { bf16x8 v; uint32_t u[4]; };

// ---------------------------------------------------------------------------
// Fused kernel: one block per batch, 4 waves, 1 block/CU (LDS-bound).
//   wave 0   : soft-DTW DP consumer (identical math to the passing round-10+
//              exp-domain linear-recurrence kernel), fed from an LDS ring.
//   waves 1-3: MFMA producers. Chunk k = D columns [32k, 32k+32): load A,B
//              fp32 from global, convert to bf16 frags in regs, 16x16x32
//              MFMA, add norms, scale by LOG2E, bf16 -> ring[col % 204].
// Sync: prod_done[k] flags (producer->consumer), cons_pp progress counter
// (consumer->producer, gates ring-wrap overwrites). No barriers after init.
// ---------------------------------------------------------------------------
__global__ __launch_bounds__(256) void fused_dtw(
        const float* __restrict__ A, const float* __restrict__ B,
        float* __restrict__ out) {
    __shared__ __align__(16) unsigned short ring[RING * RSTRIDE]; // 159,936 B
    __shared__ __align__(16) float normA[SEQN];                   //   1,536 B
    __shared__ int prod_done[16];
    __shared__ int cons_pp;

    const int bat  = blockIdx.x;
    const int tid  = threadIdx.x;
    const int wv   = tid >> 6;
    const int lane = tid & 63;

    if (tid < 16) prod_done[tid] = 0;
    if (tid == 16) cons_pp = -1;
    __syncthreads();                       // only block-wide sync in the kernel

    if (wv != 0) {
        // ========================= PRODUCERS (waves 1..3) ====================
        const int l16 = lane & 15, q = lane >> 4;
        const float* __restrict__ Ab = A + (long)bat * SEQN * DIM;
        const float* __restrict__ Bb = B + (long)bat * SEQM * DIM;
        bool first = true;                 // first chunk of THIS wave: also compute normA
        for (int k = wv - 1; k < NCHUNK; k += 3) {
            if (k >= 6) {
                // ring-wrap overwrite safety: destroyed cols <= 32k+31-204;
                // lane63 has read (and lgkm-drained, via release) all cols
                // <= 4*cons_pp-120. thr = 8k-9 leaves a 4-phase-pair margin.
                int thr = 8 * k - 9, g = 0;
                while (__hip_atomic_load(&cons_pp, __ATOMIC_ACQUIRE,
                                         __HIP_MEMORY_SCOPE_WORKGROUP) < thr)
                    if (++g > (1 << 22)) break;    // safety valve: fail, don't hang
            }
            if (k == 12) {
                // pad columns 384..387 = KINF2 (INF-flow right edge), slots 180..183
                uint32_t pv = bf16_pair(KINF2, KINF2);
                #pragma unroll
                for (int c = 0; c < 4; c++) {
                    uint32_t* p = (uint32_t*)&ring[(384 - RING + c) * RSTRIDE + 6 * lane];
                    p[0] = pv; p[1] = pv; p[2] = pv;
                }
            } else {
                // ---- B fragments for 32 cols (2 j-groups of 16) + b-norms ----
                frag_u bfrag[2][4];
                float bn[2];
                #pragma unroll
                for (int jg = 0; jg < 2; jg++) {
                    const float* bp = Bb + (long)(32 * k + jg * 16 + l16) * DIM + q * 8;
                    float s = 0.0f;
                    #pragma unroll
                    for (int kk = 0; kk < 4; kk++) {
                        float4 v0 = *(const float4*)(bp + kk * 32);
                        float4 v1 = *(const float4*)(bp + kk * 32 + 4);
                        bfrag[jg][kk].u[0] = bf16_pair(v0.x, v0.y);
                        bfrag[jg][kk].u[1] = bf16_pair(v0.z, v0.w);
                        bfrag[jg][kk].u[2] = bf16_pair(v1.x, v1.y);
                        bfrag[jg][kk].u[3] = bf16_pair(v1.z, v1.w);
                        s += v0.x*v0.x + v0.y*v0.y + v0.z*v0.z + v0.w*v0.w
                           + v1.x*v1.x + v1.y*v1.y + v1.z*v1.z + v1.w*v1.w;
                    }
                    s += __shfl_xor(s, 16, 64);
                    s += __shfl_xor(s, 32, 64);
                    bn[jg] = s;            // norm of this lane's j row
                }
                // ---- sweep the 24 A row-groups ----
                for (int si = 0; si < 24; si++) {
                    const float* ap = Ab + (long)(si * 16 + l16) * DIM + q * 8;
                    float4 a0[4], a1[4];
                    #pragma unroll
                    for (int kk = 0; kk < 4; kk++) {
                        a0[kk] = *(const float4*)(ap + kk * 32);
                        a1[kk] = *(const float4*)(ap + kk * 32 + 4);
                    }
                    frag_u afr[4];
                    #pragma unroll
                    for (int kk = 0; kk < 4; kk++) {
                        afr[kk].u[0] = bf16_pair(a0[kk].x, a0[kk].y);
                        afr[kk].u[1] = bf16_pair(a0[kk].z, a0[kk].w);
                        afr[kk].u[2] = bf16_pair(a1[kk].x, a1[kk].y);
                        afr[kk].u[3] = bf16_pair(a1[kk].z, a1[kk].w);
                    }
                    if (first) {           // each producer writes normA once (identical values)
                        float sa = 0.0f;
                        #pragma unroll
                        for (int kk = 0; kk < 4; kk++)
                            sa += a0[kk].x*a0[kk].x + a0[kk].y*a0[kk].y
                                + a0[kk].z*a0[kk].z + a0[kk].w*a0[kk].w
                                + a1[kk].x*a1[kk].x + a1[kk].y*a1[kk].y
                                + a1[kk].z*a1[kk].z + a1[kk].w*a1[kk].w;
                        sa += __shfl_xor(sa, 16, 64);
                        sa += __shfl_xor(sa, 32, 64);
                        if (q == 0) normA[si * 16 + l16] = sa;
                    }
                    f32x4 acc0 = {0.0f, 0.0f, 0.0f, 0.0f};
                    f32x4 acc1 = {0.0f, 0.0f, 0.0f, 0.0f};
                    #pragma unroll
                    for (int kk = 0; kk < 4; kk++) {
                        acc0 = __builtin_amdgcn_mfma_f32_16x16x32_bf16(
                                   afr[kk].v, bfrag[0][kk].v, acc0, 0, 0, 0);
                        acc1 = __builtin_amdgcn_mfma_f32_16x16x32_bf16(
                                   afr[kk].v, bfrag[1][kk].v, acc1, 0, 0, 0);
                    }
                    if (first) asm volatile("s_waitcnt lgkmcnt(0)" ::: "memory");
                    float4 an = *(const float4*)&normA[si * 16 + q * 4];
                    #pragma unroll
                    for (int jg = 0; jg < 2; jg++) {
                        int col  = 32 * k + jg * 16 + l16;
                        int slot = col >= RING ? col - RING : col;
                        f32x4 ac = jg ? acc1 : acc0;
                        ushort4 pk;
                        pk.x = bf16_rne((an.x + bn[jg] - 2.0f * ac[0]) * LOG2E);
                        pk.y = bf16_rne((an.y + bn[jg] - 2.0f * ac[1]) * LOG2E);
                        pk.z = bf16_rne((an.z + bn[jg] - 2.0f * ac[2]) * LOG2E);
                        pk.w = bf16_rne((an.w + bn[jg] - 2.0f * ac[3]) * LOG2E);
                        *(ushort4*)&ring[slot * RSTRIDE + si * 16 + q * 4] = pk;
                    }
                }
                first = false;
            }
            __hip_atomic_store(&prod_done[k], 1, __ATOMIC_RELEASE,
                               __HIP_MEMORY_SCOPE_WORKGROUP);
        }
        return;
    }

    // =========================== CONSUMER (wave 0) ===========================
    // Soft-DTW DP, exp-domain linear-recurrence chain — body identical to the
    // passing standalone kernel; only the refill source (LDS ring) and the
    // flag gating/publishing are new.
    const int t = lane;
    {
        int g = 0;
        while (__hip_atomic_load(&prod_done[0], __ATOMIC_ACQUIRE,
                                 __HIP_MEMORY_SCOPE_WORKGROUP) == 0)
            if (++g > (1 << 22)) break;
    }
    const unsigned short* __restrict__ ringT = ring + 6 * t;

    float prev[6];                                   // prev column's v (exact)
    #pragma unroll
    for (int r = 0; r < 6; r++) prev[r] = KINF2;

    // raw D FIFO: slot qq holds D column (c0 + qq)
    uint3 dslot[4];
    #pragma unroll
    for (int qq = 0; qq < 4; qq++) {
        int c = qq - 2 * t;
        int cc = c < 0 ? 0 : c;                      // clamp low (< RING always here)
        dslot[qq] = *(const uint3*)(ringT + cc * RSTRIDE);
    }

    float rcv0 = KINF2, rcv1 = KINF2, old_diag = KINF2;
    float lane0_diag = 0.0f;                         // R[0][0]; KINF2 afterwards
    const bool isl0 = (t == 0);
    int c0 = -2 * t;                                 // D-col of this phase's colA

#define UNPACK(d, w)                                                        \
    d[0] = __uint_as_float(w.x << 16);                                      \
    d[1] = __uint_as_float(w.x & 0xFFFF0000u);                              \
    d[2] = __uint_as_float(w.y << 16);                                      \
    d[3] = __uint_as_float(w.y & 0xFFFF0000u);                              \
    d[4] = __uint_as_float(w.z << 16);                                      \
    d[5] = __uint_as_float(w.z & 0xFFFF0000u);

#define COLPASS(dX, diag0, upseed, LEFTV, NEWV)                             \
    {                                                                       \
        float Bp = (upseed), Fp = 1.0f;                                     \
        float Bv[6], Fv[6];                                                 \
        _Pragma("unroll")                                                   \
        for (int r = 0; r < 6; r++) {                                       \
            float vd = (r == 0) ? (diag0) : LEFTV[r - 1];                   \
            float vl = LEFTV[r];                                            \
            float m3 = fminf(fminf(vd, vl), Bp);     /* v_min3_f32 */       \
            float al = EXP2F(m3 - Bp);                                      \
            float be = EXP2F(m3 - vd) + EXP2F(m3 - vl);                     \
            float Fr = __builtin_fmaf(al, Fp, be);                          \
            float Br = dX[r] + m3;                                          \
            Bv[r] = Br; Fv[r] = Fr;                                         \
            Bp = Br; Fp = Fr;                                               \
        }                                                                   \
        _Pragma("unroll")                                                   \
        for (int r = 0; r < 6; r++)                                         \
            NEWV[r] = Bv[r] - LOG2F(Fv[r]);                                 \
    }

#define PHASE2(Q)                                                           \
    {                                                                       \
        uint3 wA = dslot[Q];                                                \
        uint3 wB = dslot[(Q) + 1];                                          \
        {   /* refill both slots for phase p+2 from the LDS ring */         \
            int cnA = c0 + 4;                                               \
            int ccA = cnA < 0 ? 0 : (cnA > 387 ? 387 : cnA);                \
            int sA  = ccA >= RING ? ccA - RING : ccA;                       \
            int cnB = c0 + 5;                                               \
            int ccB = cnB < 0 ? 0 : (cnB > 387 ? 387 : cnB);                \
            int sB  = ccB >= RING ? ccB - RING : ccB;                       \
            dslot[Q]       = *(const uint3*)(ringT + sA * RSTRIDE);         \
            dslot[(Q) + 1] = *(const uint3*)(ringT + sB * RSTRIDE);         \
        }                                                                   \
        float dA[6], dB[6];                                                 \
        UNPACK(dA, wA)                                                      \
        UNPACK(dB, wB)                                                      \
        float dgA = isl0 ? lane0_diag : old_diag;                           \
        float upA = isl0 ? KINF2 : rcv0;                                    \
        float upB = isl0 ? KINF2 : rcv1;                                    \
        float newA[6];                                                      \
        COLPASS(dA, dgA, upA, prev, newA)                                   \
        COLPASS(dB, upA, upB, newA, prev)                                   \
        old_diag = rcv1;                                                    \
        rcv0 = __shfl_up(newA[5], 1, 64);                                   \
        rcv1 = __shfl_up(prev[5], 1, 64);                                   \
        lane0_diag = KINF2;                                                 \
        c0 += 2;                                                            \
    }

    for (int pp = 0; pp < 127; pp++) {               // phase pairs 0..126
        if ((pp & 7) == 7) {                         // gate next chunk (exactly covers
            int k = (4 * pp + 7) >> 5;               //  refills through pp+7)
            if (k < NCHUNK) {
                int g = 0;
                while (__hip_atomic_load(&prod_done[k], __ATOMIC_ACQUIRE,
                                         __HIP_MEMORY_SCOPE_WORKGROUP) == 0)
                    if (++g > (1 << 22)) break;
            }
        }
        PHASE2(0)
        PHASE2(2)
        if (t == 0)                                  // publish progress (release =>
            __hip_atomic_store(&cons_pp, pp,         //  wave lgkm drain: reads durable)
                               __ATOMIC_RELEASE, __HIP_MEMORY_SCOPE_WORKGROUP);
    }
    PHASE2(0)                                        // phase 254
#undef PHASE2
#undef COLPASS
#undef UNPACK

    // lane 63, last phase colB = column 383 (0-based): prev[5] = R[384][384]
    if (t == 63) out[bat] = prev[5] * LN2;
}

// ---------------------------------------------------------------------------
extern "C" void kernel_launch(void* const* d_in, const int* in_sizes, int n_in,
                              void* d_out, int out_size, void* d_ws, size_t ws_size,
                              hipStream_t stream) {
    (void)in_sizes; (void)n_in; (void)out_size; (void)d_ws; (void)ws_size;
    const float* a = (const float*)d_in[0];
    const float* b = (const float*)d_in[1];
    float* out = (float*)d_out;

    fused_dtw<<<dim3(BATCH), dim3(256), 0, stream>>>(a, b, out);
}

// Round 2
// 195.137 us; speedup vs baseline: 1.4143x; 1.4143x over previous
//
#include <hip/hip_runtime.h>
#include <stdint.h>

// Problem constants (fixed by the reference setup_inputs)
#define BATCH 128
#define SEQN  384                         // a rows (DP rows i)
#define SEQM  384                         // b rows (DP columns j)
#define DIM   128
#define KINF   1000000.0f                 // reference pseudo-infinity (nat units)
#define LOG2E  1.4426950408889634f
#define LN2    0.6931471805599453f
#define KINF2  (KINF * LOG2E)             // pseudo-infinity in base-2-scaled units

// Fused producer/consumer geometry
#define RING    204                       // LDS ring capacity in D-columns
#define RSTRIDE 392                       // ushorts per ring column (conflict-free banks)
#define NCHUNK  13                        // 0..11 = 32-col MFMA chunks; 12 = pad cols 384..387

// hardware base-2 transcendentals (v_exp_f32 / v_log_f32)
#define EXP2F(x) __builtin_amdgcn_exp2f(x)
#define LOG2F(x) __builtin_amdgcn_logf(x)

typedef __attribute__((ext_vector_type(8))) short bf16x8;   // 8 bf16 = 4 VGPRs (MFMA A/B frag)
typedef __attribute__((ext_vector_type(4))) float f32x4;    // MFMA C/D frag

__device__ __forceinline__ unsigned short bf16_rne(float x) {
    uint32_t u = __float_as_uint(x);
    u += 0x7FFFu + ((u >> 16) & 1u);
    return (unsigned short)(u >> 16);
}
__device__ __forceinline__ uint32_t bf16_pair(float x, float y) {
    uint32_t ux = __float_as_uint(x); ux += 0x7FFFu + ((ux >> 16) & 1u);
    uint32_t uy = __float_as_uint(y); uy += 0x7FFFu + ((uy >> 16) & 1u);
    return (ux >> 16) | (uy & 0xFFFF0000u);
}

union frag_u { bf16x8 v; uint32_t u[4]; };

// ---------------------------------------------------------------------------
// Fused kernel: one block per batch, 4 waves, 1 block/CU (LDS-bound).
//   wave 0   : soft-DTW DP consumer (identical math to the passing kernel).
//   waves 1-3: MFMA producers. CHANGE vs round 1: every chunk is produced by
//   ALL THREE waves in parallel (wave w owns A-rows 128(w-1)..128w-1), with a
//   1-deep software prefetch over the 8 si-groups, and the ring-wrap gate is
//   loosened to its derived safety bound (thr = 8k-12; exact bound 8k-13).
//   prod_done[k] is a counter: each wave fetch-adds 1 (release); the consumer
//   waits for ==3 (acquire). Chunk latency drops ~3x and fits the ~10-pp
//   production window enforced by ring capacity.
// ---------------------------------------------------------------------------
__global__ __launch_bounds__(256) void fused_dtw(
        const float* __restrict__ A, const float* __restrict__ B,
        float* __restrict__ out) {
    __shared__ __align__(16) unsigned short ring[RING * RSTRIDE]; // 159,936 B
    __shared__ __align__(16) float normA[SEQN];                   //   1,536 B
    __shared__ int prod_done[16];
    __shared__ int cons_pp;

    const int bat  = blockIdx.x;
    const int tid  = threadIdx.x;
    const int wv   = tid >> 6;
    const int lane = tid & 63;

    if (tid < 16) prod_done[tid] = 0;
    if (tid == 16) cons_pp = -1;
    __syncthreads();                       // only block-wide sync in the kernel

    if (wv != 0) {
        // ========================= PRODUCERS (waves 1..3) ====================
        const int l16 = lane & 15, q = lane >> 4;
        const int sbase = (wv - 1) * 8;    // this wave's si-groups: sbase..sbase+7
        const float* __restrict__ Ab = A + (long)bat * SEQN * DIM;
        const float* __restrict__ Bb = B + (long)bat * SEQM * DIM;
        bool first = true;                 // first chunk: also compute this wave's normA slice
        for (int k = 0; k < NCHUNK; k++) {
            if (k >= 6) {
                // ring-wrap safety: chunk k destroys cols <= 32k-173; last ring
                // read of col C is lane63 @ phase (C+122)/2, drained by the
                // release-publish at end of pp floor((C+122)/4). Exact bound
                // thr = 8k-13; use 8k-12 (1 pp margin).
                int thr = 8 * k - 12, g = 0;
                while (__hip_atomic_load(&cons_pp, __ATOMIC_ACQUIRE,
                                         __HIP_MEMORY_SCOPE_WORKGROUP) < thr)
                    if (++g > (1 << 22)) break;    // safety valve: fail, don't hang
            }
            if (k == 12) {
                // pad columns 384..387 = KINF2 (INF-flow right edge), slots 180..183
                if (wv == 1) {
                    uint32_t pv = bf16_pair(KINF2, KINF2);
                    #pragma unroll
                    for (int c = 0; c < 4; c++) {
                        uint32_t* p = (uint32_t*)&ring[(384 - RING + c) * RSTRIDE + 6 * lane];
                        p[0] = pv; p[1] = pv; p[2] = pv;
                    }
                }
            } else {
                // ---- B fragments for 32 cols (2 j-groups of 16) + b-norms ----
                frag_u bfrag[2][4];
                float bn[2];
                #pragma unroll
                for (int jg = 0; jg < 2; jg++) {
                    const float* bp = Bb + (long)(32 * k + jg * 16 + l16) * DIM + q * 8;
                    float s = 0.0f;
                    #pragma unroll
                    for (int kk = 0; kk < 4; kk++) {
                        float4 v0 = *(const float4*)(bp + kk * 32);
                        float4 v1 = *(const float4*)(bp + kk * 32 + 4);
                        bfrag[jg][kk].u[0] = bf16_pair(v0.x, v0.y);
                        bfrag[jg][kk].u[1] = bf16_pair(v0.z, v0.w);
                        bfrag[jg][kk].u[2] = bf16_pair(v1.x, v1.y);
                        bfrag[jg][kk].u[3] = bf16_pair(v1.z, v1.w);
                        s += v0.x*v0.x + v0.y*v0.y + v0.z*v0.z + v0.w*v0.w
                           + v1.x*v1.x + v1.y*v1.y + v1.z*v1.z + v1.w*v1.w;
                    }
                    s += __shfl_xor(s, 16, 64);
                    s += __shfl_xor(s, 32, 64);
                    bn[jg] = s;            // norm of this lane's j row
                }
                // ---- this wave's 8 si-groups, 1-deep prefetched ----
                float4 c0v[4], c1v[4];
                {
                    const float* ap = Ab + (long)(sbase * 16 + l16) * DIM + q * 8;
                    #pragma unroll
                    for (int kk = 0; kk < 4; kk++) {
                        c0v[kk] = *(const float4*)(ap + kk * 32);
                        c1v[kk] = *(const float4*)(ap + kk * 32 + 4);
                    }
                }
                #pragma unroll
                for (int s8 = 0; s8 < 8; s8++) {
                    const int si = sbase + s8;
                    float4 n0[4], n1[4];
                    if (s8 < 7) {          // prefetch next si-group
                        const float* ap = Ab + (long)((si + 1) * 16 + l16) * DIM + q * 8;
                        #pragma unroll
                        for (int kk = 0; kk < 4; kk++) {
                            n0[kk] = *(const float4*)(ap + kk * 32);
                            n1[kk] = *(const float4*)(ap + kk * 32 + 4);
                        }
                    }
                    frag_u afr[4];
                    #pragma unroll
                    for (int kk = 0; kk < 4; kk++) {
                        afr[kk].u[0] = bf16_pair(c0v[kk].x, c0v[kk].y);
                        afr[kk].u[1] = bf16_pair(c0v[kk].z, c0v[kk].w);
                        afr[kk].u[2] = bf16_pair(c1v[kk].x, c1v[kk].y);
                        afr[kk].u[3] = bf16_pair(c1v[kk].z, c1v[kk].w);
                    }
                    if (first) {           // this wave's normA slice (own rows only)
                        float sa = 0.0f;
                        #pragma unroll
                        for (int kk = 0; kk < 4; kk++)
                            sa += c0v[kk].x*c0v[kk].x + c0v[kk].y*c0v[kk].y
                                + c0v[kk].z*c0v[kk].z + c0v[kk].w*c0v[kk].w
                                + c1v[kk].x*c1v[kk].x + c1v[kk].y*c1v[kk].y
                                + c1v[kk].z*c1v[kk].z + c1v[kk].w*c1v[kk].w;
                        sa += __shfl_xor(sa, 16, 64);
                        sa += __shfl_xor(sa, 32, 64);
                        if (q == 0) normA[si * 16 + l16] = sa;
                    }
                    f32x4 acc0 = {0.0f, 0.0f, 0.0f, 0.0f};
                    f32x4 acc1 = {0.0f, 0.0f, 0.0f, 0.0f};
                    #pragma unroll
                    for (int kk = 0; kk < 4; kk++) {
                        acc0 = __builtin_amdgcn_mfma_f32_16x16x32_bf16(
                                   afr[kk].v, bfrag[0][kk].v, acc0, 0, 0, 0);
                        acc1 = __builtin_amdgcn_mfma_f32_16x16x32_bf16(
                                   afr[kk].v, bfrag[1][kk].v, acc1, 0, 0, 0);
                    }
                    if (first) asm volatile("s_waitcnt lgkmcnt(0)" ::: "memory");
                    float4 an = *(const float4*)&normA[si * 16 + q * 4];
                    #pragma unroll
                    for (int jg = 0; jg < 2; jg++) {
                        int col  = 32 * k + jg * 16 + l16;
                        int slot = col >= RING ? col - RING : col;
                        f32x4 ac = jg ? acc1 : acc0;
                        ushort4 pk;
                        pk.x = bf16_rne((an.x + bn[jg] - 2.0f * ac[0]) * LOG2E);
                        pk.y = bf16_rne((an.y + bn[jg] - 2.0f * ac[1]) * LOG2E);
                        pk.z = bf16_rne((an.z + bn[jg] - 2.0f * ac[2]) * LOG2E);
                        pk.w = bf16_rne((an.w + bn[jg] - 2.0f * ac[3]) * LOG2E);
                        *(ushort4*)&ring[slot * RSTRIDE + si * 16 + q * 4] = pk;
                    }
                    if (s8 < 7) {          // rotate prefetch stage
                        #pragma unroll
                        for (int kk = 0; kk < 4; kk++) { c0v[kk] = n0[kk]; c1v[kk] = n1[kk]; }
                    }
                }
                first = false;
            }
            __hip_atomic_fetch_add(&prod_done[k], 1, __ATOMIC_RELEASE,
                                   __HIP_MEMORY_SCOPE_WORKGROUP);
        }
        return;
    }

    // =========================== CONSUMER (wave 0) ===========================
    // Soft-DTW DP, exp-domain linear-recurrence chain — body identical to the
    // passing kernel; only the done-count (==3) differs from round 1.
    const int t = lane;
    {
        int g = 0;
        while (__hip_atomic_load(&prod_done[0], __ATOMIC_ACQUIRE,
                                 __HIP_MEMORY_SCOPE_WORKGROUP) < 3)
            if (++g > (1 << 22)) break;
    }
    const unsigned short* __restrict__ ringT = ring + 6 * t;

    float prev[6];                                   // prev column's v (exact)
    #pragma unroll
    for (int r = 0; r < 6; r++) prev[r] = KINF2;

    // raw D FIFO: slot qq holds D column (c0 + qq)
    uint3 dslot[4];
    #pragma unroll
    for (int qq = 0; qq < 4; qq++) {
        int c = qq - 2 * t;
        int cc = c < 0 ? 0 : c;                      // clamp low (< RING always here)
        dslot[qq] = *(const uint3*)(ringT + cc * RSTRIDE);
    }

    float rcv0 = KINF2, rcv1 = KINF2, old_diag = KINF2;
    float lane0_diag = 0.0f;                         // R[0][0]; KINF2 afterwards
    const bool isl0 = (t == 0);
    int c0 = -2 * t;                                 // D-col of this phase's colA

#define UNPACK(d, w)                                                        \
    d[0] = __uint_as_float(w.x << 16);                                      \
    d[1] = __uint_as_float(w.x & 0xFFFF0000u);                              \
    d[2] = __uint_as_float(w.y << 16);                                      \
    d[3] = __uint_as_float(w.y & 0xFFFF0000u);                              \
    d[4] = __uint_as_float(w.z << 16);                                      \
    d[5] = __uint_as_float(w.z & 0xFFFF0000u);

#define COLPASS(dX, diag0, upseed, LEFTV, NEWV)                             \
    {                                                                       \
        float Bp = (upseed), Fp = 1.0f;                                     \
        float Bv[6], Fv[6];                                                 \
        _Pragma("unroll")                                                   \
        for (int r = 0; r < 6; r++) {                                       \
            float vd = (r == 0) ? (diag0) : LEFTV[r - 1];                   \
            float vl = LEFTV[r];                                            \
            float m3 = fminf(fminf(vd, vl), Bp);     /* v_min3_f32 */       \
            float al = EXP2F(m3 - Bp);                                      \
            float be = EXP2F(m3 - vd) + EXP2F(m3 - vl);                     \
            float Fr = __builtin_fmaf(al, Fp, be);                          \
            float Br = dX[r] + m3;                                          \
            Bv[r] = Br; Fv[r] = Fr;                                         \
            Bp = Br; Fp = Fr;                                               \
        }                                                                   \
        _Pragma("unroll")                                                   \
        for (int r = 0; r < 6; r++)                                         \
            NEWV[r] = Bv[r] - LOG2F(Fv[r]);                                 \
    }

#define PHASE2(Q)                                                           \
    {                                                                       \
        uint3 wA = dslot[Q];                                                \
        uint3 wB = dslot[(Q) + 1];                                          \
        {   /* refill both slots for phase p+2 from the LDS ring */         \
            int cnA = c0 + 4;                                               \
            int ccA = cnA < 0 ? 0 : (cnA > 387 ? 387 : cnA);                \
            int sA  = ccA >= RING ? ccA - RING : ccA;                       \
            int cnB = c0 + 5;                                               \
            int ccB = cnB < 0 ? 0 : (cnB > 387 ? 387 : cnB);                \
            int sB  = ccB >= RING ? ccB - RING : ccB;                       \
            dslot[Q]       = *(const uint3*)(ringT + sA * RSTRIDE);         \
            dslot[(Q) + 1] = *(const uint3*)(ringT + sB * RSTRIDE);         \
        }                                                                   \
        float dA[6], dB[6];                                                 \
        UNPACK(dA, wA)                                                      \
        UNPACK(dB, wB)                                                      \
        float dgA = isl0 ? lane0_diag : old_diag;                           \
        float upA = isl0 ? KINF2 : rcv0;                                    \
        float upB = isl0 ? KINF2 : rcv1;                                    \
        float newA[6];                                                      \
        COLPASS(dA, dgA, upA, prev, newA)                                   \
        COLPASS(dB, upA, upB, newA, prev)                                   \
        old_diag = rcv1;                                                    \
        rcv0 = __shfl_up(newA[5], 1, 64);                                   \
        rcv1 = __shfl_up(prev[5], 1, 64);                                   \
        lane0_diag = KINF2;                                                 \
        c0 += 2;                                                            \
    }

    for (int pp = 0; pp < 127; pp++) {               // phase pairs 0..126
        if ((pp & 7) == 7) {                         // gate chunk k: first use is
            int k = (4 * pp + 7) >> 5;               //  the refills of this pp
            if (k < NCHUNK) {
                int g = 0;
                while (__hip_atomic_load(&prod_done[k], __ATOMIC_ACQUIRE,
                                         __HIP_MEMORY_SCOPE_WORKGROUP) < 3)
                    if (++g > (1 << 22)) break;
            }
        }
        PHASE2(0)
        PHASE2(2)
        if (t == 0)                                  // publish progress (release =>
            __hip_atomic_store(&cons_pp, pp,         //  wave lgkm drain: reads durable)
                               __ATOMIC_RELEASE, __HIP_MEMORY_SCOPE_WORKGROUP);
    }
    PHASE2(0)                                        // phase 254
#undef PHASE2
#undef COLPASS
#undef UNPACK

    // lane 63, last phase colB = column 383 (0-based): prev[5] = R[384][384]
    if (t == 63) out[bat] = prev[5] * LN2;
}

// ---------------------------------------------------------------------------
extern "C" void kernel_launch(void* const* d_in, const int* in_sizes, int n_in,
                              void* d_out, int out_size, void* d_ws, size_t ws_size,
                              hipStream_t stream) {
    (void)in_sizes; (void)n_in; (void)out_size; (void)d_ws; (void)ws_size;
    const float* a = (const float*)d_in[0];
    const float* b = (const float*)d_in[1];
    float* out = (float*)d_out;

    fused_dtw<<<dim3(BATCH), dim3(256), 0, stream>>>(a, b, out);
}